// Round 1
// baseline (271.221 us; speedup 1.0000x reference)
//
#include <hip/hip_runtime.h>
#include <math.h>

// Problem constants (SparseGate): B=16384, D=2048, E=64, k=2
#define NROWS 16384
#define DDIM  2048
#define NEXP  64
#define NCOL  128   // gate cols (64) + noise cols (64) fused

constexpr int BM = 128;   // rows per block
constexpr int BN = 128;   // cols per block (all of them)
constexpr int BK = 32;    // k-chunk
constexpr int TM = 8;     // micro-tile rows per thread
constexpr int TN = 8;     // micro-tile cols per thread
// threads = (BM/TM)*(BN/TN) = 16*16 = 256

// ---------------------------------------------------------------------------
// GEMM: part[split][row][c] = sum_{k in split} x[row][k] * W'[c][k]
// where W'[c] = gate_weights[c] for c<64, noise_weights[c-64] for c>=64.
// ---------------------------------------------------------------------------
__global__ __launch_bounds__(256) void gemm_kernel(
    const float* __restrict__ x,
    const float* __restrict__ gw,
    const float* __restrict__ nw,
    float* __restrict__ part,
    int k_per_split)
{
    __shared__ __align__(16) float xs[BK][BM + 4];   // k-major, padded
    __shared__ __align__(16) float wsh[BK][BN + 4];  // k-major, padded

    const int tid = threadIdx.x;
    const int tx = tid & 15;          // col group
    const int ty = tid >> 4;          // row group
    const int m0 = ty * TM;
    const int n0 = tx * TN;

    const int row_tile = blockIdx.x;          // 0..127
    const int split    = blockIdx.y;          // 0..S-1
    const int row_base = row_tile * BM;
    const int k_begin  = split * k_per_split;

    // staging coords: 8 threads per row, float4 each -> 32 k per row-pass
    const int sr = tid >> 3;          // 0..31
    const int sk = (tid & 7) * 4;     // 0,4,...,28

    float acc[TM][TN];
    #pragma unroll
    for (int i = 0; i < TM; ++i)
        #pragma unroll
        for (int j = 0; j < TN; ++j) acc[i][j] = 0.f;

    for (int kc = 0; kc < k_per_split; kc += BK) {
        const int kg = k_begin + kc;

        // ---- stage x tile (transposed into LDS) ----
        #pragma unroll
        for (int p = 0; p < 4; ++p) {
            const int r = sr + p * 32;
            float4 v = *(const float4*)&x[(size_t)(row_base + r) * DDIM + kg + sk];
            xs[sk + 0][r] = v.x; xs[sk + 1][r] = v.y;
            xs[sk + 2][r] = v.z; xs[sk + 3][r] = v.w;
        }
        // ---- stage W tile (transposed into LDS) ----
        #pragma unroll
        for (int p = 0; p < 4; ++p) {
            const int e = sr + p * 32;
            const float* wp = (e < NEXP) ? &gw[(size_t)e * DDIM]
                                         : &nw[(size_t)(e - NEXP) * DDIM];
            float4 v = *(const float4*)&wp[kg + sk];
            wsh[sk + 0][e] = v.x; wsh[sk + 1][e] = v.y;
            wsh[sk + 2][e] = v.z; wsh[sk + 3][e] = v.w;
        }
        __syncthreads();

        // ---- micro-kernel ----
        #pragma unroll
        for (int kk = 0; kk < BK; ++kk) {
            float a[TM], b[TN];
            *(float4*)&a[0] = *(const float4*)&xs[kk][m0];
            *(float4*)&a[4] = *(const float4*)&xs[kk][m0 + 4];
            *(float4*)&b[0] = *(const float4*)&wsh[kk][n0];
            *(float4*)&b[4] = *(const float4*)&wsh[kk][n0 + 4];
            #pragma unroll
            for (int i = 0; i < TM; ++i)
                #pragma unroll
                for (int j = 0; j < TN; ++j)
                    acc[i][j] += a[i] * b[j];
        }
        __syncthreads();
    }

    // ---- write partials ----
    float* pp = part + ((size_t)split * NROWS + row_base) * NCOL;
    #pragma unroll
    for (int i = 0; i < TM; ++i) {
        float4 v0 = make_float4(acc[i][0], acc[i][1], acc[i][2], acc[i][3]);
        float4 v1 = make_float4(acc[i][4], acc[i][5], acc[i][6], acc[i][7]);
        *(float4*)&pp[(size_t)(m0 + i) * NCOL + n0]     = v0;
        *(float4*)&pp[(size_t)(m0 + i) * NCOL + n0 + 4] = v1;
    }
}

// ---------------------------------------------------------------------------
// Epilogue per row (one wave per row, lane = expert):
// ew = clean + noise * softplus(noisy); top-k; softmax over selected; scatter.
// ---------------------------------------------------------------------------
__device__ __forceinline__ void gate_epilogue(
    int row, int lane, float clean, float noisy,
    const float* __restrict__ noise, int k, float* __restrict__ out)
{
    // softplus(x) = max(x,0) + log1p(exp(-|x|))
    const float sp = fmaxf(noisy, 0.f) + log1pf(expf(-fabsf(noisy)));
    const float ew = clean + noise[(size_t)row * NEXP + lane] * sp;

    float cur = ew;           // masked working copy
    const float myv = ew;
    float m0 = 0.f, denom = 0.f;
    int selected = 0;

    for (int t = 0; t < k; ++t) {
        float v = cur;
        int idx = lane;
        #pragma unroll
        for (int off = 32; off; off >>= 1) {
            const float ov = __shfl_xor(v, off);
            const int   oi = __shfl_xor(idx, off);
            if (ov > v || (ov == v && oi < idx)) { v = ov; idx = oi; }
        }
        if (t == 0) m0 = v;            // running max = first selected
        denom += expf(v - m0);         // all lanes: same broadcast value
        if (lane == idx) { selected = 1; cur = -INFINITY; }
    }

    const float val = selected ? expf(myv - m0) / denom : 0.f;
    out[(size_t)row * NEXP + lane] = val;
}

__global__ __launch_bounds__(256) void gate_kernel(
    const float* __restrict__ part,
    const float* __restrict__ noise,
    const int* __restrict__ kptr,
    float* __restrict__ out,
    int S)
{
    const int lane = threadIdx.x & 63;
    const int wave = threadIdx.x >> 6;
    const int row  = blockIdx.x * 4 + wave;
    if (row >= NROWS) return;

    int k = kptr[0];
    if (k < 1) k = 1;
    if (k > NEXP) k = NEXP;

    float clean = 0.f, noisy = 0.f;
    for (int s = 0; s < S; ++s) {
        const float* p = part + ((size_t)s * NROWS + row) * NCOL;
        clean += p[lane];
        noisy += p[NEXP + lane];
    }
    gate_epilogue(row, lane, clean, noisy, noise, k, out);
}

// ---------------------------------------------------------------------------
// Fallback (only if workspace is too small): direct per-row dot products.
// Slow but correct; never expected to run with a sane ws_size.
// ---------------------------------------------------------------------------
__global__ __launch_bounds__(256) void naive_kernel(
    const float* __restrict__ x,
    const float* __restrict__ gw,
    const float* __restrict__ nw,
    const float* __restrict__ noise,
    const int* __restrict__ kptr,
    float* __restrict__ out)
{
    const int lane = threadIdx.x & 63;
    const int wave = threadIdx.x >> 6;
    const int row  = blockIdx.x * 4 + wave;
    if (row >= NROWS) return;

    int k = kptr[0];
    if (k < 1) k = 1;
    if (k > NEXP) k = NEXP;

    const float* xr = x  + (size_t)row  * DDIM;
    const float* g  = gw + (size_t)lane * DDIM;
    const float* w2 = nw + (size_t)lane * DDIM;
    float c = 0.f, n = 0.f;
    for (int d = 0; d < DDIM; ++d) {
        const float xv = xr[d];
        c += xv * g[d];
        n += xv * w2[d];
    }
    gate_epilogue(row, lane, c, n, noise, k, out);
}

// ---------------------------------------------------------------------------
extern "C" void kernel_launch(void* const* d_in, const int* in_sizes, int n_in,
                              void* d_out, int out_size, void* d_ws, size_t ws_size,
                              hipStream_t stream)
{
    const float* x     = (const float*)d_in[0];
    const float* gw    = (const float*)d_in[1];
    const float* nw    = (const float*)d_in[2];
    const float* noise = (const float*)d_in[3];
    const int*   kptr  = (const int*)d_in[4];
    float* out  = (float*)d_out;
    float* part = (float*)d_ws;

    const size_t bytes_per_split = (size_t)NROWS * NCOL * sizeof(float); // 8.4 MB
    int S = 0;
    if      (ws_size >= 4 * bytes_per_split) S = 4;
    else if (ws_size >= 2 * bytes_per_split) S = 2;
    else if (ws_size >= 1 * bytes_per_split) S = 1;

    if (S > 0) {
        dim3 grid(NROWS / BM, S);
        hipLaunchKernelGGL(gemm_kernel, grid, dim3(256), 0, stream,
                           x, gw, nw, part, DDIM / S);
        hipLaunchKernelGGL(gate_kernel, dim3(NROWS / 4), dim3(256), 0, stream,
                           part, noise, kptr, out, S);
    } else {
        hipLaunchKernelGGL(naive_kernel, dim3(NROWS / 4), dim3(256), 0, stream,
                           x, gw, nw, noise, kptr, out);
    }
}